// Round 8
// baseline (247.768 us; speedup 1.0000x reference)
//
#include <hip/hip_runtime.h>

// Dtypes (R1-R6 forensics): floats fp32, edges int32 [E][2], output fp32.
// Workspace intermediates: bf16 (MFMA path).
// Spill law: local arrays with MFMA force scratch; named scalars only.
// R10: XCD-chunked swizzle (m204) + reg-prefetch: 235.6 -> 228.9 us.
// R11-R12 (REVERTED): one-barrier dbuf = +15.8us. Law: PREFETCH loads issued just before
//   __syncthreads get drained (vmcnt(0)-before-s_barrier). Loads that MUST complete
//   before the barrier are exempt (single-stage staging is fine).
// R13: 1024-thread attn = null; attn is memory-system-bound (168MB random gathers, LLC).
// R14: diag split -> gemm1 visible: 46.6us, MfmaUtil 12.4%, 95% barrier-locked stall.
// R15 (REJECTED): no-LDS GEMM = 84.4us. Scattered frag lines, no reuse. LDS earns its cost.
// R16 (R7): 512-thread blocks: gemm1 40.8us, MfmaUtil 14.5%, VGPR 44. Lockstep remains.
//   ALSO: fillBufferAligned x2 @ 40.7us (262MB re-poison, 82% HBM) inside measured window
//   -- ~81us fixed harness overhead we cannot touch. Controllable compute ~150us.
// R17 (this): single-stage GEMM -- whole K=256 staged once (132KB LDS, 1 block/CU),
//   ONE barrier per block, then 8 unrolled ks-steps of pure ds_read+MFMA. Removes all
//   per-K-step barrier drains. Staging writes 32B-interleaved (conflict-free). attn
//   merged back to one dispatch (diag split paid out; recoup ~4us).
//   Guard: gemm WRITE ~60MB (inflation = spill -> revert R7 gemm).

typedef __bf16 bf16x8 __attribute__((ext_vector_type(8)));
typedef float  f32x4  __attribute__((ext_vector_type(4)));

__device__ __forceinline__ float bf2f(unsigned short u) {
    union { unsigned int i; float f; } v; v.i = ((unsigned int)u) << 16; return v.f;
}
__device__ __forceinline__ unsigned short f2bf(float f) {
    union { float f; unsigned int i; } v; v.f = f;
    unsigned int x = v.i;
    unsigned int r = (x + 0x7FFFu + ((x >> 16) & 1u)) >> 16;   // RNE
    return (unsigned short)r;
}

#define NNODE 20000
#define ROWS  40000      // B*N
#define DMODEL 256

// ---------- K0: fused prep (blocks 0..1023) + LayerNorm1 (blocks 1024..6023) ----------
__global__ __launch_bounds__(256) void prep_ln1_kernel(
    const float* __restrict__ wq, const float* __restrict__ wk,
    const float* __restrict__ wv, const float* __restrict__ wo,
    const float* __restrict__ bq, const float* __restrict__ bk,
    const float* __restrict__ bv, const float* __restrict__ bo,
    const float* __restrict__ x,
    const float* __restrict__ g1, const float* __restrict__ b1,
    unsigned short* __restrict__ Wqkvt,   // [768][256] bf16
    unsigned short* __restrict__ Wot,     // [256][256] bf16
    float* __restrict__ biasq,            // [768]
    float* __restrict__ biaso,            // [256]
    unsigned short* __restrict__ xn)      // [ROWS][256] bf16
{
    if (blockIdx.x < 1024) {
        int idx = blockIdx.x * 256 + threadIdx.x;
        if (idx < 768 * 256) {
            int n = idx >> 8, k = idx & 255;
            int sel = n >> 8, nl = n & 255;
            const float* w = (sel == 0) ? wq : (sel == 1) ? wk : wv;
            Wqkvt[idx] = f2bf(w[k * 256 + nl]);
        } else {
            int idx2 = idx - 768 * 256;        // [0, 65536)
            int n = idx2 >> 8, k = idx2 & 255;
            Wot[idx2] = f2bf(wo[k * 256 + n]);
        }
        if (idx < 768) {
            const float* bb = (idx < 256) ? bq : (idx < 512) ? bk : bv;
            biasq[idx] = bb[idx & 255];
        }
        if (idx >= 768 && idx < 1024) biaso[idx - 768] = bo[idx - 768];
        return;
    }
    // ---- LN1: half-wave (32 lanes) per row, 8 elems/lane ----
    int wave = threadIdx.x >> 6, lane = threadIdx.x & 63;
    int sub = lane >> 5, hl = lane & 31;
    int m = (blockIdx.x - 1024) * 8 + wave * 2 + sub;
    const float* xp = x + (size_t)m * DMODEL + hl * 8;
    float4 x0 = *(const float4*)xp;
    float4 x1 = *(const float4*)(xp + 4);
    float f[8] = {x0.x, x0.y, x0.z, x0.w, x1.x, x1.y, x1.z, x1.w};
    float s = 0.f, ss = 0.f;
    #pragma unroll
    for (int t = 0; t < 8; ++t) { s += f[t]; ss += f[t]*f[t]; }
    #pragma unroll
    for (int mk = 1; mk < 32; mk <<= 1) { s += __shfl_xor(s, mk); ss += __shfl_xor(ss, mk); }
    float mu  = s * (1.f/256.f);
    float var = ss * (1.f/256.f) - mu*mu;
    float rs  = rsqrtf(var + 1e-3f);
    float4 g0 = *(const float4*)(g1 + hl * 8);
    float4 g1v = *(const float4*)(g1 + hl * 8 + 4);
    float4 b0 = *(const float4*)(b1 + hl * 8);
    float4 b1v = *(const float4*)(b1 + hl * 8 + 4);
    float gg[8] = {g0.x, g0.y, g0.z, g0.w, g1v.x, g1v.y, g1v.z, g1v.w};
    float bb[8] = {b0.x, b0.y, b0.z, b0.w, b1v.x, b1v.y, b1v.z, b1v.w};
    unsigned short o[8];
    #pragma unroll
    for (int t = 0; t < 8; ++t) o[t] = f2bf((f[t] - mu) * rs * gg[t] + bb[t]);
    *(int4*)(xn + (size_t)m * DMODEL + hl * 8) = *(const int4*)o;
}

// ---------- K2/K4: bf16 MFMA GEMM, 128x128 tile, K=256 SINGLE-STAGE, 512 thr ----------
// C = A[M][256] @ Bt[Ncols][256]^T + bias.  EPI: relu + resid, write fp32; else bf16.
// Whole K staged once: As/Bs [128][264] bf16 (132KB LDS, 1 block/CU). One barrier,
// then 8 unrolled ks-steps of ds_read+MFMA, no further sync. Staging: thread t owns
// row t>>2, 32B column slots (t&3)*16 + j*64 -- writes conflict-free (32B interleave),
// reads 2-way (free) via +8-short row pad. Wave grid 4m x 2n: 32x64 output per wave.
#define LDSW 264   // 256 + 8 pad
#define MFMA_BF16(d, a, b) d = __builtin_amdgcn_mfma_f32_16x16x32_bf16(a, b, d, 0, 0, 0)

template<bool EPI>
__global__ __launch_bounds__(512, 1) void gemm_kernel(
    const unsigned short* __restrict__ A,
    const unsigned short* __restrict__ Bt,
    const float* __restrict__ bias,
    void* __restrict__ C,
    const unsigned short* __restrict__ resid,
    int M, int Ncols)
{
    __shared__ unsigned short As[128 * LDSW];
    __shared__ unsigned short Bs[128 * LDSW];
    int tid  = threadIdx.x;
    int wave = tid >> 6, lane = tid & 63;
    int quad = lane >> 4, l16 = lane & 15;

    // XCD-chunked bijective swizzle (m204)
    int nt_total = Ncols >> 7;
    int nwg = gridDim.x;
    int xcd = blockIdx.x & 7, loc = blockIdx.x >> 3;
    int qq = nwg >> 3, rr = nwg & 7;
    int wid = (xcd < rr) ? (xcd * (qq + 1) + loc)
                         : (rr * (qq + 1) + (xcd - rr) * qq + loc);
    int mt = wid / nt_total;
    int nt = wid - mt * nt_total;
    int m0 = mt * 128, n0 = nt * 128;
    int wm = (wave >> 1) * 32, wn = (wave & 1) * 64;   // 4m x 2n wave grid

    // ---- single-stage: whole [128][256] A and B tiles -> LDS, one barrier ----
    int srow = tid >> 2;            // 0..127
    int c16  = (tid & 3) * 16;      // 32B column slot base
    int arow = m0 + srow; if (arow >= M) arow = M - 1;   // tail dup, discarded
    const unsigned short* Ap = A  + (size_t)arow * 256 + c16;
    const unsigned short* Bp = Bt + (size_t)(n0 + srow) * 256 + c16;
    unsigned short* AsP = &As[srow * LDSW + c16];
    unsigned short* BsP = &Bs[srow * LDSW + c16];
    #pragma unroll
    for (int j = 0; j < 4; ++j) {             // 4 x (2+2) int4 = 256B/thread each array
        int4 a0 = *(const int4*)(Ap + j * 64);
        int4 a1 = *(const int4*)(Ap + j * 64 + 8);
        int4 b0 = *(const int4*)(Bp + j * 64);
        int4 b1 = *(const int4*)(Bp + j * 64 + 8);
        *(int4*)(AsP + j * 64)     = a0;
        *(int4*)(AsP + j * 64 + 8) = a1;
        *(int4*)(BsP + j * 64)     = b0;
        *(int4*)(BsP + j * 64 + 8) = b1;
    }
    __syncthreads();                          // the ONLY barrier

    f32x4 acc00 = {}, acc01 = {}, acc02 = {}, acc03 = {};
    f32x4 acc10 = {}, acc11 = {}, acc12 = {}, acc13 = {};

    #pragma unroll
    for (int ks = 0; ks < 256; ks += 32) {    // 8 pure compute steps, no sync
        int ca = ks + quad * 8;
        bf16x8 a0 = *(const bf16x8*)&As[(wm +  0 + l16) * LDSW + ca];
        bf16x8 a1 = *(const bf16x8*)&As[(wm + 16 + l16) * LDSW + ca];
        bf16x8 b0 = *(const bf16x8*)&Bs[(wn +  0 + l16) * LDSW + ca];
        bf16x8 b1 = *(const bf16x8*)&Bs[(wn + 16 + l16) * LDSW + ca];
        bf16x8 b2 = *(const bf16x8*)&Bs[(wn + 32 + l16) * LDSW + ca];
        bf16x8 b3 = *(const bf16x8*)&Bs[(wn + 48 + l16) * LDSW + ca];
        MFMA_BF16(acc00, a0, b0); MFMA_BF16(acc01, a0, b1);
        MFMA_BF16(acc02, a0, b2); MFMA_BF16(acc03, a0, b3);
        MFMA_BF16(acc10, a1, b0); MFMA_BF16(acc11, a1, b1);
        MFMA_BF16(acc12, a1, b2); MFMA_BF16(acc13, a1, b3);
    }

#define EPI_STORE(accv, R, CC) do {                                          \
        int col = n0 + wn + (CC) * 16 + l16;                                 \
        float bb = bias[col];                                                \
        int rowb = m0 + wm + (R) * 16 + quad * 4;                            \
        _Pragma("unroll")                                                    \
        for (int rr = 0; rr < 4; ++rr) {                                     \
            int row = rowb + rr;                                             \
            if (row < M) {                                                   \
                float v = (accv)[rr] + bb;                                   \
                if (EPI) {                                                   \
                    v = fmaxf(v, 0.f);                                       \
                    v += bf2f(resid[(size_t)row * 256 + col]);               \
                    ((float*)C)[(size_t)row * Ncols + col] = v;              \
                } else {                                                     \
                    ((unsigned short*)C)[(size_t)row * Ncols + col] = f2bf(v);\
                }                                                            \
            }                                                                \
        }                                                                    \
    } while (0)

    EPI_STORE(acc00, 0, 0); EPI_STORE(acc01, 0, 1); EPI_STORE(acc02, 0, 2); EPI_STORE(acc03, 0, 3);
    EPI_STORE(acc10, 1, 0); EPI_STORE(acc11, 1, 1); EPI_STORE(acc12, 1, 2); EPI_STORE(acc13, 1, 3);
#undef EPI_STORE
}

// ---------- K3: edge attention + residual + LN2 — wave = node, half-wave = batch ----------
// All 16 K/V gather loads issued into named registers before compute (R9; no spill).
// R17: merged back to one dispatch (diag split paid out). 1024 threads, 1250 blocks.
__global__ __launch_bounds__(1024) void attn_kernel(
    const unsigned short* __restrict__ qkv,   // [ROWS][768] bf16: q|k|v
    const int* __restrict__ edges,            // int32 [E][2]
    const unsigned short* __restrict__ xn,    // [ROWS][256] bf16
    const float* __restrict__ g2, const float* __restrict__ b2,
    unsigned short* __restrict__ concat,      // [ROWS][256] bf16
    unsigned short* __restrict__ h2)          // [ROWS][256] bf16
{
    int wave = threadIdx.x >> 6, lane = threadIdx.x & 63;
    int i = blockIdx.x * 16 + wave;           // node id
    int b = lane >> 5, hl = lane & 31;        // batch half, 8 dims/lane
    size_t m = (size_t)b * NNODE + i;

    int jv = 0;
    if (lane < 8) jv = edges[2 * (i * 8 + lane) + 1];   // chain head: issue first

    int4 qi = *(const int4*)(qkv + m * 768 + hl * 8);
    int4 xi = *(const int4*)(xn + m * DMODEL + hl * 8);   // issued early, used late
    const unsigned short* qs = (const unsigned short*)&qi;
    float qf[8];
    #pragma unroll
    for (int t = 0; t < 8; ++t) qf[t] = bf2f(qs[t]);

#define KVLOAD(E)                                                                  \
    int j##E = __shfl(jv, E);                                                      \
    const unsigned short* kp##E = qkv + ((size_t)b * NNODE + j##E) * 768 + 256 + hl * 8; \
    int4 KI##E = *(const int4*)(kp##E);                                            \
    int4 VI##E = *(const int4*)(kp##E + 256);
    KVLOAD(0) KVLOAD(1) KVLOAD(2) KVLOAD(3)
    KVLOAD(4) KVLOAD(5) KVLOAD(6) KVLOAD(7)
#undef KVLOAD

    float acc[8] = {};
    float den = 0.f;
    const float scale = 0.17677669529663687f;           // 1/sqrt(32)
#define EDGE(E) do {                                                         \
        const unsigned short* ks = (const unsigned short*)&KI##E;            \
        const unsigned short* vs = (const unsigned short*)&VI##E;            \
        float dot = 0.f;                                                     \
        _Pragma("unroll")                                                    \
        for (int t = 0; t < 8; ++t) dot += qf[t] * bf2f(ks[t]);              \
        dot += __shfl_xor(dot, 1);                                           \
        dot += __shfl_xor(dot, 2);            /* head = 4 lanes (dh=32) */   \
        float w = __expf(dot * scale);                                       \
        _Pragma("unroll")                                                    \
        for (int t = 0; t < 8; ++t) acc[t] += w * bf2f(vs[t]);               \
        den += w;                                                            \
    } while (0)
    EDGE(0); EDGE(1); EDGE(2); EDGE(3);
    EDGE(4); EDGE(5); EDGE(6); EDGE(7);
#undef EDGE
    float inv = 1.f / den;

    const unsigned short* xs = (const unsigned short*)&xi;
    float c[8], s = 0.f, ss = 0.f;
    #pragma unroll
    for (int t = 0; t < 8; ++t) { c[t] = bf2f(xs[t]) + acc[t] * inv; s += c[t]; ss += c[t]*c[t]; }
    #pragma unroll
    for (int mk = 1; mk < 32; mk <<= 1) { s += __shfl_xor(s, mk); ss += __shfl_xor(ss, mk); }
    float mu  = s * (1.f/256.f);
    float var = ss * (1.f/256.f) - mu*mu;
    float rs  = rsqrtf(var + 1e-3f);

    float4 ga = *(const float4*)(g2 + hl * 8);
    float4 gb = *(const float4*)(g2 + hl * 8 + 4);
    float4 ba = *(const float4*)(b2 + hl * 8);
    float4 bb = *(const float4*)(b2 + hl * 8 + 4);
    float gg[8] = {ga.x, ga.y, ga.z, ga.w, gb.x, gb.y, gb.z, gb.w};
    float bv[8] = {ba.x, ba.y, ba.z, ba.w, bb.x, bb.y, bb.z, bb.w};
    unsigned short oc[8], oh[8];
    #pragma unroll
    for (int t = 0; t < 8; ++t) {
        oc[t] = f2bf(c[t]);
        oh[t] = f2bf((c[t] - mu) * rs * gg[t] + bv[t]);
    }
    *(int4*)(concat + m * DMODEL + hl * 8) = *(const int4*)oc;
    *(int4*)(h2     + m * DMODEL + hl * 8) = *(const int4*)oh;
}

// ---------- launch ----------
extern "C" void kernel_launch(void* const* d_in, const int* in_sizes, int n_in,
                              void* d_out, int out_size, void* d_ws, size_t ws_size,
                              hipStream_t stream)
{
    const float* x   = (const float*)d_in[0];
    const int* edges = (const int*)d_in[1];
    const float* wq = (const float*)d_in[2];
    const float* bq = (const float*)d_in[3];
    const float* wk = (const float*)d_in[4];
    const float* bk = (const float*)d_in[5];
    const float* wv = (const float*)d_in[6];
    const float* bv = (const float*)d_in[7];
    const float* wo = (const float*)d_in[8];
    const float* bo = (const float*)d_in[9];
    const float* g1 = (const float*)d_in[10];
    const float* b1 = (const float*)d_in[11];
    const float* g2 = (const float*)d_in[12];
    const float* b2 = (const float*)d_in[13];

    char* ws = (char*)d_ws;
    unsigned short* Wqkvt = (unsigned short*)(ws);                    // 393216 B
    unsigned short* Wot   = (unsigned short*)(ws + 393216);           // 131072 B
    float* biasq          = (float*)(ws + 393216 + 131072);           // 3072 B
    float* biaso          = (float*)(ws + 393216 + 131072 + 3072);    // 1024 B
    size_t off = 393216 + 131072 + 4096;
    unsigned short* xn     = (unsigned short*)(ws + off); off += (size_t)ROWS * DMODEL * 2;
    unsigned short* qkv    = (unsigned short*)(ws + off); off += (size_t)ROWS * 768 * 2;
    unsigned short* concat = (unsigned short*)(ws + off); off += (size_t)ROWS * DMODEL * 2;
    unsigned short* h2     = (unsigned short*)(ws + off); off += (size_t)ROWS * DMODEL * 2;

    prep_ln1_kernel<<<1024 + ROWS / 8, 256, 0, stream>>>(
        wq, wk, wv, wo, bq, bk, bv, bo, x, g1, b1, Wqkvt, Wot, biasq, biaso, xn);
    gemm_kernel<false><<<dim3(313 * 6), 512, 0, stream>>>(xn, Wqkvt, biasq, qkv, nullptr, ROWS, 768);
    attn_kernel<<<NNODE / 16, 1024, 0, stream>>>(qkv, edges, xn, g2, b2, concat, h2);
    gemm_kernel<true><<<dim3(313 * 2), 512, 0, stream>>>(h2, Wot, biaso, d_out, concat, ROWS, 256);
}

// Round 9
// 225.750 us; speedup vs baseline: 1.0975x; 1.0975x over previous
//
#include <hip/hip_runtime.h>

// Dtypes (R1-R6 forensics): floats fp32, edges int32 [E][2], output fp32.
// Workspace intermediates: bf16 (MFMA path).
// Spill law: local arrays with MFMA force scratch; named scalars only.
// R10: XCD-chunked swizzle (m204) + reg-prefetch: 235.6 -> 228.9 us.
// R11-R12 LAW: every __syncthreads drains vmcnt(0). A load's usable overlap is
//   issue-point -> end-of-iteration barrier. Issue loads at ITERATION TOP, never
//   just before a barrier.
// R13: 1024-thread attn = null; attn memory-system-bound (168MB random gathers, LLC).
// R14: diag split -> gemm1: 46.6us, MfmaUtil 12.4%, 95% barrier-locked stall.
// R15 (REJECTED): no-LDS GEMM = 84.4us. Scattered frag lines, no reuse.
// R16 (R7): 512-thr blocks: gemm1 40.8us, MfmaUtil 14.5%, VGPR 44, 2 blocks/CU.
//   fillBufferAligned x2 @ 40.7us (262MB re-poison) = ~81us fixed harness overhead.
// R17 (R8, REJECTED): single-stage 132KB LDS -> 1 block/CU, staging exposed serially
//   per block: +17us. LDS staging needs >=2 blocks/CU to self-overlap.
// R18 (this): R7 gemm + corrected double-buffer (T3/T14 minimum 2-phase):
//   64-col dbuf (72KB LDS, keeps 2 blocks/CU), ONE barrier per K-step, tile-(i+2)
//   loads issued at iteration TOP (full compute-phase overlap before the drain),
//   ds_write of tile i+1 waits on nothing (its loads drained at previous barrier).
//   Two named reg sets (+16 VGPR). Barriers/block 8 -> 4. attn stays merged.
//   Guard: delta vs R8 is pure gemm; if total >= ~225 revert to plain R7 gemm.

typedef __bf16 bf16x8 __attribute__((ext_vector_type(8)));
typedef float  f32x4  __attribute__((ext_vector_type(4)));

__device__ __forceinline__ float bf2f(unsigned short u) {
    union { unsigned int i; float f; } v; v.i = ((unsigned int)u) << 16; return v.f;
}
__device__ __forceinline__ unsigned short f2bf(float f) {
    union { float f; unsigned int i; } v; v.f = f;
    unsigned int x = v.i;
    unsigned int r = (x + 0x7FFFu + ((x >> 16) & 1u)) >> 16;   // RNE
    return (unsigned short)r;
}

#define NNODE 20000
#define ROWS  40000      // B*N
#define DMODEL 256

// ---------- K0: fused prep (blocks 0..1023) + LayerNorm1 (blocks 1024..6023) ----------
__global__ __launch_bounds__(256) void prep_ln1_kernel(
    const float* __restrict__ wq, const float* __restrict__ wk,
    const float* __restrict__ wv, const float* __restrict__ wo,
    const float* __restrict__ bq, const float* __restrict__ bk,
    const float* __restrict__ bv, const float* __restrict__ bo,
    const float* __restrict__ x,
    const float* __restrict__ g1, const float* __restrict__ b1,
    unsigned short* __restrict__ Wqkvt,   // [768][256] bf16
    unsigned short* __restrict__ Wot,     // [256][256] bf16
    float* __restrict__ biasq,            // [768]
    float* __restrict__ biaso,            // [256]
    unsigned short* __restrict__ xn)      // [ROWS][256] bf16
{
    if (blockIdx.x < 1024) {
        int idx = blockIdx.x * 256 + threadIdx.x;
        if (idx < 768 * 256) {
            int n = idx >> 8, k = idx & 255;
            int sel = n >> 8, nl = n & 255;
            const float* w = (sel == 0) ? wq : (sel == 1) ? wk : wv;
            Wqkvt[idx] = f2bf(w[k * 256 + nl]);
        } else {
            int idx2 = idx - 768 * 256;        // [0, 65536)
            int n = idx2 >> 8, k = idx2 & 255;
            Wot[idx2] = f2bf(wo[k * 256 + n]);
        }
        if (idx < 768) {
            const float* bb = (idx < 256) ? bq : (idx < 512) ? bk : bv;
            biasq[idx] = bb[idx & 255];
        }
        if (idx >= 768 && idx < 1024) biaso[idx - 768] = bo[idx - 768];
        return;
    }
    // ---- LN1: half-wave (32 lanes) per row, 8 elems/lane ----
    int wave = threadIdx.x >> 6, lane = threadIdx.x & 63;
    int sub = lane >> 5, hl = lane & 31;
    int m = (blockIdx.x - 1024) * 8 + wave * 2 + sub;
    const float* xp = x + (size_t)m * DMODEL + hl * 8;
    float4 x0 = *(const float4*)xp;
    float4 x1 = *(const float4*)(xp + 4);
    float f[8] = {x0.x, x0.y, x0.z, x0.w, x1.x, x1.y, x1.z, x1.w};
    float s = 0.f, ss = 0.f;
    #pragma unroll
    for (int t = 0; t < 8; ++t) { s += f[t]; ss += f[t]*f[t]; }
    #pragma unroll
    for (int mk = 1; mk < 32; mk <<= 1) { s += __shfl_xor(s, mk); ss += __shfl_xor(ss, mk); }
    float mu  = s * (1.f/256.f);
    float var = ss * (1.f/256.f) - mu*mu;
    float rs  = rsqrtf(var + 1e-3f);
    float4 g0 = *(const float4*)(g1 + hl * 8);
    float4 g1v = *(const float4*)(g1 + hl * 8 + 4);
    float4 b0 = *(const float4*)(b1 + hl * 8);
    float4 b1v = *(const float4*)(b1 + hl * 8 + 4);
    float gg[8] = {g0.x, g0.y, g0.z, g0.w, g1v.x, g1v.y, g1v.z, g1v.w};
    float bb[8] = {b0.x, b0.y, b0.z, b0.w, b1v.x, b1v.y, b1v.z, b1v.w};
    unsigned short o[8];
    #pragma unroll
    for (int t = 0; t < 8; ++t) o[t] = f2bf((f[t] - mu) * rs * gg[t] + bb[t]);
    *(int4*)(xn + (size_t)m * DMODEL + hl * 8) = *(const int4*)o;
}

// ---------- K2/K4: bf16 MFMA GEMM, 128x128 tile, BK=64, dbuf 1-barrier, 512 thr ----------
// C = A[M][256] @ Bt[Ncols][256]^T + bias.  EPI: relu + resid, write fp32; else bf16.
// Wave grid 4m x 2n (32x64 out/wave, acc 32 VGPR). Dbuf: As/Bs[2][128][72] (72KB,
// 2 blocks/CU). Per iteration: {load tile i+2 (TOP), compute buf[i&1], ds_write
// buf[(i+1)&1], barrier}. One barrier per K-step; writes never wait on vmcnt.
#define LDS_W 72          // 64 + 8 pad
#define BUFSZ (128 * LDS_W)
#define MFMA_BF16(d, a, b) d = __builtin_amdgcn_mfma_f32_16x16x32_bf16(a, b, d, 0, 0, 0)

template<bool EPI>
__global__ __launch_bounds__(512, 2) void gemm_kernel(
    const unsigned short* __restrict__ A,
    const unsigned short* __restrict__ Bt,
    const float* __restrict__ bias,
    void* __restrict__ C,
    const unsigned short* __restrict__ resid,
    int M, int Ncols)
{
    __shared__ unsigned short As[2 * BUFSZ];
    __shared__ unsigned short Bs[2 * BUFSZ];
    int tid  = threadIdx.x;
    int wave = tid >> 6, lane = tid & 63;
    int quad = lane >> 4, l16 = lane & 15;

    // XCD-chunked bijective swizzle (m204)
    int nt_total = Ncols >> 7;
    int nwg = gridDim.x;
    int xcd = blockIdx.x & 7, loc = blockIdx.x >> 3;
    int qq = nwg >> 3, rr = nwg & 7;
    int wid = (xcd < rr) ? (xcd * (qq + 1) + loc)
                         : (rr * (qq + 1) + (xcd - rr) * qq + loc);
    int mt = wid / nt_total;
    int nt = wid - mt * nt_total;
    int m0 = mt * 128, n0 = nt * 128;
    int wm = (wave >> 1) * 32, wn = (wave & 1) * 64;   // 4m x 2n wave grid

    int srow = tid >> 2;            // 0..127
    int scol = (tid & 3) * 16;      // 32B column slot of the 64-short k-slice
    int arow = m0 + srow; if (arow >= M) arow = M - 1;   // tail dup, discarded
    const unsigned short* Ap = A  + (size_t)arow * 256 + scol;
    const unsigned short* Bp = Bt + (size_t)(n0 + srow) * 256 + scol;
    unsigned short* AsP = &As[srow * LDS_W + scol];
    unsigned short* BsP = &Bs[srow * LDS_W + scol];

    f32x4 acc00 = {}, acc01 = {}, acc02 = {}, acc03 = {};
    f32x4 acc10 = {}, acc11 = {}, acc12 = {}, acc13 = {};

    int4 s0a0, s0a1, s0b0, s0b1;    // reg set 0 (tiles 0,2)
    int4 s1a0, s1a1, s1b0, s1b1;    // reg set 1 (tiles 1,3)

#define STAGE_LOAD(S, KT) do {                         \
        S##a0 = *(const int4*)(Ap + (KT) * 64);        \
        S##a1 = *(const int4*)(Ap + (KT) * 64 + 8);    \
        S##b0 = *(const int4*)(Bp + (KT) * 64);        \
        S##b1 = *(const int4*)(Bp + (KT) * 64 + 8);    \
    } while (0)
#define STAGE_WRITE(S, BUF) do {                       \
        *(int4*)(AsP + (BUF) * BUFSZ)     = S##a0;     \
        *(int4*)(AsP + (BUF) * BUFSZ + 8) = S##a1;     \
        *(int4*)(BsP + (BUF) * BUFSZ)     = S##b0;     \
        *(int4*)(BsP + (BUF) * BUFSZ + 8) = S##b1;     \
    } while (0)
#define COMPUTE(BUF) do {                                                          \
        _Pragma("unroll")                                                          \
        for (int ks = 0; ks < 64; ks += 32) {                                      \
            int ca = (BUF) * BUFSZ + ks + quad * 8;                                \
            bf16x8 a0 = *(const bf16x8*)&As[ca + (wm +  0 + l16) * LDS_W];         \
            bf16x8 a1 = *(const bf16x8*)&As[ca + (wm + 16 + l16) * LDS_W];         \
            bf16x8 b0 = *(const bf16x8*)&Bs[ca + (wn +  0 + l16) * LDS_W];         \
            bf16x8 b1 = *(const bf16x8*)&Bs[ca + (wn + 16 + l16) * LDS_W];         \
            bf16x8 b2 = *(const bf16x8*)&Bs[ca + (wn + 32 + l16) * LDS_W];         \
            bf16x8 b3 = *(const bf16x8*)&Bs[ca + (wn + 48 + l16) * LDS_W];         \
            MFMA_BF16(acc00, a0, b0); MFMA_BF16(acc01, a0, b1);                    \
            MFMA_BF16(acc02, a0, b2); MFMA_BF16(acc03, a0, b3);                    \
            MFMA_BF16(acc10, a1, b0); MFMA_BF16(acc11, a1, b1);                    \
            MFMA_BF16(acc12, a1, b2); MFMA_BF16(acc13, a1, b3);                    \
        }                                                                          \
    } while (0)

    // prologue: tiles 0,1 in flight; tile0 -> buf0; one barrier
    STAGE_LOAD(s0, 0);
    STAGE_LOAD(s1, 1);
    STAGE_WRITE(s0, 0);             // compiler waits vmcnt for s0 only
    __syncthreads();                // drains s1 loads too (one-time)

    // iter0: compute tile0(buf0); write tile1->buf1; load tile2 at top
    STAGE_LOAD(s0, 2);
    COMPUTE(0);
    STAGE_WRITE(s1, 1);             // s1 already drained at prologue barrier
    __syncthreads();

    // iter1: compute tile1(buf1); write tile2->buf0; load tile3 at top
    STAGE_LOAD(s1, 3);
    COMPUTE(1);
    STAGE_WRITE(s0, 0);             // s0 drained at iter0 barrier
    __syncthreads();

    // iter2: compute tile2(buf0); write tile3->buf1
    COMPUTE(0);
    STAGE_WRITE(s1, 1);             // s1 drained at iter1 barrier
    __syncthreads();

    // iter3: compute tile3(buf1); no barrier
    COMPUTE(1);

#undef STAGE_LOAD
#undef STAGE_WRITE
#undef COMPUTE

#define EPI_STORE(accv, R, CC) do {                                          \
        int col = n0 + wn + (CC) * 16 + l16;                                 \
        float bb = bias[col];                                                \
        int rowb = m0 + wm + (R) * 16 + quad * 4;                            \
        _Pragma("unroll")                                                    \
        for (int rr = 0; rr < 4; ++rr) {                                     \
            int row = rowb + rr;                                             \
            if (row < M) {                                                   \
                float v = (accv)[rr] + bb;                                   \
                if (EPI) {                                                   \
                    v = fmaxf(v, 0.f);                                       \
                    v += bf2f(resid[(size_t)row * 256 + col]);               \
                    ((float*)C)[(size_t)row * Ncols + col] = v;              \
                } else {                                                     \
                    ((unsigned short*)C)[(size_t)row * Ncols + col] = f2bf(v);\
                }                                                            \
            }                                                                \
        }                                                                    \
    } while (0)

    EPI_STORE(acc00, 0, 0); EPI_STORE(acc01, 0, 1); EPI_STORE(acc02, 0, 2); EPI_STORE(acc03, 0, 3);
    EPI_STORE(acc10, 1, 0); EPI_STORE(acc11, 1, 1); EPI_STORE(acc12, 1, 2); EPI_STORE(acc13, 1, 3);
#undef EPI_STORE
}

// ---------- K3: edge attention + residual + LN2 — wave = node, half-wave = batch ----------
// All 16 K/V gather loads issued into named registers before compute (R9; no spill).
// Merged single dispatch; 1024 threads, 1250 blocks. At its random-gather floor (R13).
__global__ __launch_bounds__(1024) void attn_kernel(
    const unsigned short* __restrict__ qkv,   // [ROWS][768] bf16: q|k|v
    const int* __restrict__ edges,            // int32 [E][2]
    const unsigned short* __restrict__ xn,    // [ROWS][256] bf16
    const float* __restrict__ g2, const float* __restrict__ b2,
    unsigned short* __restrict__ concat,      // [ROWS][256] bf16
    unsigned short* __restrict__ h2)          // [ROWS][256] bf16
{
    int wave = threadIdx.x >> 6, lane = threadIdx.x & 63;
    int i = blockIdx.x * 16 + wave;           // node id
    int b = lane >> 5, hl = lane & 31;        // batch half, 8 dims/lane
    size_t m = (size_t)b * NNODE + i;

    int jv = 0;
    if (lane < 8) jv = edges[2 * (i * 8 + lane) + 1];   // chain head: issue first

    int4 qi = *(const int4*)(qkv + m * 768 + hl * 8);
    int4 xi = *(const int4*)(xn + m * DMODEL + hl * 8);   // issued early, used late
    const unsigned short* qs = (const unsigned short*)&qi;
    float qf[8];
    #pragma unroll
    for (int t = 0; t < 8; ++t) qf[t] = bf2f(qs[t]);

#define KVLOAD(E)                                                                  \
    int j##E = __shfl(jv, E);                                                      \
    const unsigned short* kp##E = qkv + ((size_t)b * NNODE + j##E) * 768 + 256 + hl * 8; \
    int4 KI##E = *(const int4*)(kp##E);                                            \
    int4 VI##E = *(const int4*)(kp##E + 256);
    KVLOAD(0) KVLOAD(1) KVLOAD(2) KVLOAD(3)
    KVLOAD(4) KVLOAD(5) KVLOAD(6) KVLOAD(7)
#undef KVLOAD

    float acc[8] = {};
    float den = 0.f;
    const float scale = 0.17677669529663687f;           // 1/sqrt(32)
#define EDGE(E) do {                                                         \
        const unsigned short* ks = (const unsigned short*)&KI##E;            \
        const unsigned short* vs = (const unsigned short*)&VI##E;            \
        float dot = 0.f;                                                     \
        _Pragma("unroll")                                                    \
        for (int t = 0; t < 8; ++t) dot += qf[t] * bf2f(ks[t]);              \
        dot += __shfl_xor(dot, 1);                                           \
        dot += __shfl_xor(dot, 2);            /* head = 4 lanes (dh=32) */   \
        float w = __expf(dot * scale);                                       \
        _Pragma("unroll")                                                    \
        for (int t = 0; t < 8; ++t) acc[t] += w * bf2f(vs[t]);               \
        den += w;                                                            \
    } while (0)
    EDGE(0); EDGE(1); EDGE(2); EDGE(3);
    EDGE(4); EDGE(5); EDGE(6); EDGE(7);
#undef EDGE
    float inv = 1.f / den;

    const unsigned short* xs = (const unsigned short*)&xi;
    float c[8], s = 0.f, ss = 0.f;
    #pragma unroll
    for (int t = 0; t < 8; ++t) { c[t] = bf2f(xs[t]) + acc[t] * inv; s += c[t]; ss += c[t]*c[t]; }
    #pragma unroll
    for (int mk = 1; mk < 32; mk <<= 1) { s += __shfl_xor(s, mk); ss += __shfl_xor(ss, mk); }
    float mu  = s * (1.f/256.f);
    float var = ss * (1.f/256.f) - mu*mu;
    float rs  = rsqrtf(var + 1e-3f);

    float4 ga = *(const float4*)(g2 + hl * 8);
    float4 gb = *(const float4*)(g2 + hl * 8 + 4);
    float4 ba = *(const float4*)(b2 + hl * 8);
    float4 bb = *(const float4*)(b2 + hl * 8 + 4);
    float gg[8] = {ga.x, ga.y, ga.z, ga.w, gb.x, gb.y, gb.z, gb.w};
    float bv[8] = {ba.x, ba.y, ba.z, ba.w, bb.x, bb.y, bb.z, bb.w};
    unsigned short oc[8], oh[8];
    #pragma unroll
    for (int t = 0; t < 8; ++t) {
        oc[t] = f2bf(c[t]);
        oh[t] = f2bf((c[t] - mu) * rs * gg[t] + bv[t]);
    }
    *(int4*)(concat + m * DMODEL + hl * 8) = *(const int4*)oc;
    *(int4*)(h2     + m * DMODEL + hl * 8) = *(const int4*)oh;
}

// ---------- launch ----------
extern "C" void kernel_launch(void* const* d_in, const int* in_sizes, int n_in,
                              void* d_out, int out_size, void* d_ws, size_t ws_size,
                              hipStream_t stream)
{
    const float* x   = (const float*)d_in[0];
    const int* edges = (const int*)d_in[1];
    const float* wq = (const float*)d_in[2];
    const float* bq = (const float*)d_in[3];
    const float* wk = (const float*)d_in[4];
    const float* bk = (const float*)d_in[5];
    const float* wv = (const float*)d_in[6];
    const float* bv = (const float*)d_in[7];
    const float* wo = (const float*)d_in[8];
    const float* bo = (const float*)d_in[9];
    const float* g1 = (const float*)d_in[10];
    const float* b1 = (const float*)d_in[11];
    const float* g2 = (const float*)d_in[12];
    const float* b2 = (const float*)d_in[13];

    char* ws = (char*)d_ws;
    unsigned short* Wqkvt = (unsigned short*)(ws);                    // 393216 B
    unsigned short* Wot   = (unsigned short*)(ws + 393216);           // 131072 B
    float* biasq          = (float*)(ws + 393216 + 131072);           // 3072 B
    float* biaso          = (float*)(ws + 393216 + 131072 + 3072);    // 1024 B
    size_t off = 393216 + 131072 + 4096;
    unsigned short* xn     = (unsigned short*)(ws + off); off += (size_t)ROWS * DMODEL * 2;
    unsigned short* qkv    = (unsigned short*)(ws + off); off += (size_t)ROWS * 768 * 2;
    unsigned short* concat = (unsigned short*)(ws + off); off += (size_t)ROWS * DMODEL * 2;
    unsigned short* h2     = (unsigned short*)(ws + off); off += (size_t)ROWS * DMODEL * 2;

    prep_ln1_kernel<<<1024 + ROWS / 8, 256, 0, stream>>>(
        wq, wk, wv, wo, bq, bk, bv, bo, x, g1, b1, Wqkvt, Wot, biasq, biaso, xn);
    gemm_kernel<false><<<dim3(313 * 6), 512, 0, stream>>>(xn, Wqkvt, biasq, qkv, nullptr, ROWS, 768);
    attn_kernel<<<NNODE / 16, 1024, 0, stream>>>(qkv, edges, xn, g2, b2, concat, h2);
    gemm_kernel<true><<<dim3(313 * 2), 512, 0, stream>>>(h2, Wot, biaso, d_out, concat, ROWS, 256);
}